// Round 22
// baseline (199.713 us; speedup 1.0000x reference)
//
#include <hip/hip_runtime.h>

typedef short bf16x8 __attribute__((ext_vector_type(8)));
typedef float f32x4 __attribute__((ext_vector_type(4)));
typedef unsigned short u16;

#define S_LEN 2048
#define DM 1024
#define NH 16
#define DK 64
#define BHD ((size_t)S_LEN * DK) /* elements per (b,h) head = 131072 */

// Q projection pre-scale: 1/sqrt(dk) * log2(e). Folded into the Wq conversion.
#define QSCALE 0.18033688011112042f

static __device__ __forceinline__ u16 f2bf(float f) {
  union { float f; unsigned u; } x; x.f = f;
  unsigned r = x.u + 0x7FFFu + ((x.u >> 16) & 1u);
  return (u16)(r >> 16);
}

// async global->LDS, 16B per lane, linear LDS dest (wave-uniform base + lane*16)
static __device__ __forceinline__ void gload_lds16(const u16* g, u16* l) {
  __builtin_amdgcn_global_load_lds(
      (const __attribute__((address_space(1))) unsigned int*)g,
      (__attribute__((address_space(3))) unsigned int*)l, 16, 0, 0);
}

// ---------------- f32 -> bf16 conversion for the 4 weight matrices only -------------------
__global__ __launch_bounds__(256) void conv_w(
    const float* __restrict__ Wq, const float* __restrict__ Wk,
    const float* __restrict__ Wv, const float* __restrict__ Wo,
    u16* __restrict__ wb) {
  const int b = blockIdx.x;
  const int wsel = b >> 10;
  const float* s = (wsel == 0) ? Wq : (wsel == 1) ? Wk : (wsel == 2) ? Wv : Wo;
  const float sc = (wsel == 0) ? QSCALE : 1.0f;
  u16* d = wb + (size_t)wsel * 1048576;
  int i = (b & 1023) * 256 + threadIdx.x;
  float4 vv = ((const float4*)s)[i];
  ushort4 h;
  h.x = f2bf(vv.x * sc); h.y = f2bf(vv.y * sc);
  h.z = f2bf(vv.z * sc); h.w = f2bf(vv.w * sc);
  ((ushort4*)d)[i] = h;
}

// ============ BK=32 tile machinery (R22): [128 rows][32 cols] bf16 = 8KB/buffer ===========
// Row = 4 chunks of 16B; stored chunk c holds global chunk c^(row&3).
// Staging thread t: rows j*64 + (t>>2) (j=0,1), stored chunk (t&3); LDS offset j*2048 + t*8
// u16 = linear (identity (t>>2)*4+(t&3)=t) -> wave-uniform base + lane*16B for gload_lds.
// Fragment read: lane (lg,lr) wants global chunk lg of row ..+lr -> position lg^(lr&3).

// bf16 source staging via global_load_lds (B tiles, oproj A)
#define GSTAGE32(DST, SRC, K0)                                                    \
  {                                                                               \
    _Pragma("unroll") for (int j = 0; j < 2; ++j) {                               \
      gload_lds16((SRC) + (size_t)(j * 64 + srow) * 1024 + (K0) + schnk * 8,      \
                  (DST) + j * 2048 + w * 512);                                    \
    }                                                                             \
  }

// f32 A staging: load 8 floats (one chunk-to-be) per j to regs; later cvt+ds_write 16B
#define ASTAGE_LOAD32(R, SRCF, K0)                                                \
  {                                                                               \
    _Pragma("unroll") for (int j = 0; j < 2; ++j) {                               \
      const float* p_ = (SRCF) + (size_t)(m0 + j * 64 + srow) * 1024 + (K0) + schnk * 8; \
      R[j][0] = *(const float4*)(p_);                                             \
      R[j][1] = *(const float4*)(p_ + 4);                                         \
    }                                                                             \
  }
#define ASTAGE_WRITE32(DST, R)                                                    \
  {                                                                               \
    _Pragma("unroll") for (int j = 0; j < 2; ++j) {                               \
      unsigned u0, u1, u2, u3;                                                    \
      asm("v_cvt_pk_bf16_f32 %0, %1, %2" : "=v"(u0) : "v"(R[j][0].x), "v"(R[j][0].y)); \
      asm("v_cvt_pk_bf16_f32 %0, %1, %2" : "=v"(u1) : "v"(R[j][0].z), "v"(R[j][0].w)); \
      asm("v_cvt_pk_bf16_f32 %0, %1, %2" : "=v"(u2) : "v"(R[j][1].x), "v"(R[j][1].y)); \
      asm("v_cvt_pk_bf16_f32 %0, %1, %2" : "=v"(u3) : "v"(R[j][1].z), "v"(R[j][1].w)); \
      uint4 pk_; pk_.x = u0; pk_.y = u1; pk_.z = u2; pk_.w = u3;                  \
      *(uint4*)((DST) + (size_t)(j * 2048 + t * 8)) = pk_;                        \
    }                                                                             \
  }

// ---------------- fused QKV projection GEMM: Y = X(f32) @ Wb^T (+ bias*bscale) ------------
// BK=32 double-buffered (32KB LDS -> 5 blocks/CU; R21 was 2 blocks/CU and stall-bound).
// A write-at-top pipeline (R21-proven): write A(i+1) after barrier, loads for i+2 early.
__global__ __launch_bounds__(256) void proj_gemm(
    const float* __restrict__ qf32, const float* __restrict__ kf32,
    const float* __restrict__ vf32, const u16* __restrict__ wb,
    const float* __restrict__ bq, const float* __restrict__ bk, const float* __restrict__ bv,
    u16* __restrict__ qws, u16* __restrict__ kws, u16* __restrict__ vws)
{
  __shared__ u16 Al[2][128 * 32];
  __shared__ u16 Bl[2][128 * 32];
  const int z = blockIdx.z;
  const float* Xf = (z == 0) ? qf32 : (z == 1) ? kf32 : vf32;
  const u16* Wb = wb + (size_t)z * 1048576;
  const float* bias = (z == 0) ? bq : (z == 1) ? bk : bv;
  const float bscale = (z == 0) ? QSCALE : 1.0f;

  const int t = threadIdx.x;
  const int l = t & 63, w = t >> 6;
  const int lr = l & 15, lg = l >> 4;
  const int wm = w >> 1, wn = w & 1;
  const int m0 = blockIdx.x * 128, n0 = blockIdx.y * 128;
  const int sx4 = lr & 3;
  const int srow = t >> 2;                 // 0..63
  const int schnk = (t & 3) ^ (srow & 3);  // inverse-swizzled source chunk

  f32x4 acc[4][4] = {};
  float4 areg[2][2];

  // prologue: tile 0 staged, tile 1 loads in flight
  ASTAGE_LOAD32(areg, Xf, 0)
  GSTAGE32(&Bl[0][0], Wb + (size_t)n0 * 1024, 0)
  ASTAGE_WRITE32(&Al[0][0], areg)
  ASTAGE_LOAD32(areg, Xf, 32)

  for (int i = 0; i < 32; ++i) {
    __syncthreads();
    if (i < 31) {
      ASTAGE_WRITE32(&Al[(i + 1) & 1][0], areg)
      GSTAGE32(&Bl[(i + 1) & 1][0], Wb + (size_t)n0 * 1024, (i + 1) * 32)
    }
    if (i < 30) ASTAGE_LOAD32(areg, Xf, (i + 2) * 32)

    const u16* Ab_ = &Al[i & 1][0];
    const u16* Bb_ = &Bl[i & 1][0];

    bf16x8 a[4], b[4];
#pragma unroll
    for (int mi = 0; mi < 4; ++mi)
      a[mi] = *(const bf16x8*)(Ab_ + (wm * 64 + mi * 16 + lr) * 32 + ((lg ^ sx4) * 8));
#pragma unroll
    for (int ni = 0; ni < 4; ++ni)
      b[ni] = *(const bf16x8*)(Bb_ + (wn * 64 + ni * 16 + lr) * 32 + ((lg ^ sx4) * 8));
    __builtin_amdgcn_s_setprio(1);
#pragma unroll
    for (int mi = 0; mi < 4; ++mi)
#pragma unroll
      for (int ni = 0; ni < 4; ++ni)
        acc[mi][ni] = __builtin_amdgcn_mfma_f32_16x16x32_bf16(a[mi], b[ni], acc[mi][ni], 0, 0, 0);
    __builtin_amdgcn_s_setprio(0);
  }

#pragma unroll
  for (int mi = 0; mi < 4; ++mi) {
#pragma unroll
    for (int ni = 0; ni < 4; ++ni) {
#pragma unroll
      for (int r = 0; r < 4; ++r) {
        int m = m0 + wm * 64 + mi * 16 + lg * 4 + r;
        int n = n0 + wn * 64 + ni * 16 + lr;
        float y = acc[mi][ni][r] + bias[n] * bscale;
        u16 h = f2bf(y);
        int b_ = m >> 11, s = m & 2047, hh = n >> 6, d = n & 63;
        size_t head = (size_t)(b_ * NH + hh);
        if (z == 0)      qws[head * BHD + (size_t)s * DK + d] = h;
        else if (z == 1) kws[head * BHD + (size_t)s * DK + d] = h;
        else             vws[head * BHD + (size_t)d * S_LEN + s] = h;  // V transposed
      }
    }
  }
}

// ---------------- output projection GEMM: out = Ab(bf16) @ Wob^T + bo (fp32 out) ----------
// BK=32 double-buffered, both operands via global_load_lds.
__global__ __launch_bounds__(256) void oproj_gemm(
    const u16* __restrict__ Ab, const u16* __restrict__ Wob,
    const float* __restrict__ bo, float* __restrict__ out)
{
  __shared__ u16 Al[2][128 * 32];
  __shared__ u16 Bl[2][128 * 32];
  const int t = threadIdx.x;
  const int l = t & 63, w = t >> 6;
  const int lr = l & 15, lg = l >> 4;
  const int wm = w >> 1, wn = w & 1;
  const int m0 = blockIdx.x * 128, n0 = blockIdx.y * 128;
  const int sx4 = lr & 3;
  const int srow = t >> 2;
  const int schnk = (t & 3) ^ (srow & 3);

  f32x4 acc[4][4] = {};

  GSTAGE32(&Al[0][0], Ab + (size_t)m0 * 1024, 0)
  GSTAGE32(&Bl[0][0], Wob + (size_t)n0 * 1024, 0)

  for (int i = 0; i < 32; ++i) {
    __syncthreads();
    if (i < 31) {
      GSTAGE32(&Al[(i + 1) & 1][0], Ab + (size_t)m0 * 1024, (i + 1) * 32)
      GSTAGE32(&Bl[(i + 1) & 1][0], Wob + (size_t)n0 * 1024, (i + 1) * 32)
    }
    const u16* Ab_ = &Al[i & 1][0];
    const u16* Bb_ = &Bl[i & 1][0];

    bf16x8 a[4], b[4];
#pragma unroll
    for (int mi = 0; mi < 4; ++mi)
      a[mi] = *(const bf16x8*)(Ab_ + (wm * 64 + mi * 16 + lr) * 32 + ((lg ^ sx4) * 8));
#pragma unroll
    for (int ni = 0; ni < 4; ++ni)
      b[ni] = *(const bf16x8*)(Bb_ + (wn * 64 + ni * 16 + lr) * 32 + ((lg ^ sx4) * 8));
    __builtin_amdgcn_s_setprio(1);
#pragma unroll
    for (int mi = 0; mi < 4; ++mi)
#pragma unroll
      for (int ni = 0; ni < 4; ++ni)
        acc[mi][ni] = __builtin_amdgcn_mfma_f32_16x16x32_bf16(a[mi], b[ni], acc[mi][ni], 0, 0, 0);
    __builtin_amdgcn_s_setprio(0);
  }

#pragma unroll
  for (int mi = 0; mi < 4; ++mi) {
#pragma unroll
    for (int ni = 0; ni < 4; ++ni) {
#pragma unroll
      for (int r = 0; r < 4; ++r) {
        int m = m0 + wm * 64 + mi * 16 + lg * 4 + r;
        int n = n0 + wn * 64 + ni * 16 + lr;
        out[(size_t)m * DM + n] = acc[mi][ni][r] + bo[n];
      }
    }
  }
}

// ---------------- flash attention (unchanged from R16 — validated) -------------------------
__global__ __launch_bounds__(256, 4) void attn_kernel(
    const u16* __restrict__ qh, const u16* __restrict__ kh,
    const u16* __restrict__ vt, u16* __restrict__ aout)
{
  __shared__ u16 KT[2][64 * 64];
  __shared__ u16 VT[2][64 * 64];

  const int t = threadIdx.x;
  const int l = t & 63, w = t >> 6;      // 4 waves
  const int lr = l & 15, lg = l >> 4;

  const int bid = blockIdx.x;
  const int logical = (bid & 7) * 128 + (bid >> 3);
  const int bh = logical >> 4;               // 16 blocks per head
  const int qb = (logical & 15) * 128 + w * 32;

  const u16* qp = qh + (size_t)bh * BHD;
  const u16* kp = kh + (size_t)bh * BHD;
  const u16* vp = vt + (size_t)bh * BHD;
  const int sx = lr & 7;

  const int srow = t >> 3;                   // 0..31
  const int scolS = (t & 7) ^ (srow & 7);    // inverse-swizzled source 16B-chunk

  bf16x8 qf[2][2];
#pragma unroll
  for (int qi = 0; qi < 2; ++qi)
#pragma unroll
    for (int c = 0; c < 2; ++c)
      qf[qi][c] = *(const bf16x8*)(qp + (size_t)(qb + qi * 16 + lr) * DK + c * 32 + lg * 8);

  bf16x8 onesf;
#pragma unroll
  for (int e = 0; e < 8; ++e) onesf[e] = (short)0x3F80;

  f32x4 acc[4][2] = {};
  f32x4 acc_l[2] = {};

#define STAGE(B, KV)                                                                  \
  {                                                                                   \
    _Pragma("unroll") for (int j = 0; j < 2; ++j) {                                   \
      gload_lds16(kp + (size_t)((KV) + j * 32 + srow) * DK + scolS * 8,               \
                  &KT[B][j * 2048 + w * 512]);                                        \
      gload_lds16(vp + (size_t)(j * 32 + srow) * S_LEN + (KV) + scolS * 8,            \
                  &VT[B][j * 2048 + w * 512]);                                        \
    }                                                                                 \
  }

  STAGE(0, 0)

  for (int i = 0; i < 32; ++i) {
    __syncthreads();
    if (i < 31) STAGE((i + 1) & 1, (i + 1) * 64)

    const u16* Kb = &KT[i & 1][0];
    const u16* Vb = &VT[i & 1][0];

    f32x4 sc[4][2] = {};
    __builtin_amdgcn_s_setprio(1);
#pragma unroll
    for (int ct = 0; ct < 4; ++ct) {
      bf16x8 k0 = *(const bf16x8*)(Kb + (ct * 16 + lr) * 64 + ((lg ^ sx) * 8));
      bf16x8 k1 = *(const bf16x8*)(Kb + (ct * 16 + lr) * 64 + (((4 + lg) ^ sx) * 8));
      sc[ct][0] = __builtin_amdgcn_mfma_f32_16x16x32_bf16(k0, qf[0][0], sc[ct][0], 0, 0, 0);
      sc[ct][0] = __builtin_amdgcn_mfma_f32_16x16x32_bf16(k1, qf[0][1], sc[ct][0], 0, 0, 0);
      sc[ct][1] = __builtin_amdgcn_mfma_f32_16x16x32_bf16(k0, qf[1][0], sc[ct][1], 0, 0, 0);
      sc[ct][1] = __builtin_amdgcn_mfma_f32_16x16x32_bf16(k1, qf[1][1], sc[ct][1], 0, 0, 0);
    }
    __builtin_amdgcn_s_setprio(0);

    unsigned cpk[2][4][2];
#pragma unroll
    for (int qi = 0; qi < 2; ++qi) {
#pragma unroll
      for (int ct = 0; ct < 4; ++ct) {
        float p0 = __builtin_amdgcn_exp2f(sc[ct][qi][0]);
        float p1 = __builtin_amdgcn_exp2f(sc[ct][qi][1]);
        float p2 = __builtin_amdgcn_exp2f(sc[ct][qi][2]);
        float p3 = __builtin_amdgcn_exp2f(sc[ct][qi][3]);
        asm("v_cvt_pk_bf16_f32 %0, %1, %2" : "=v"(cpk[qi][ct][0]) : "v"(p0), "v"(p1));
        asm("v_cvt_pk_bf16_f32 %0, %1, %2" : "=v"(cpk[qi][ct][1]) : "v"(p2), "v"(p3));
      }
    }

    bf16x8 pf[2][2];
#pragma unroll
    for (int qi = 0; qi < 2; ++qi)
#pragma unroll
      for (int kk = 0; kk < 2; ++kk) {
        unsigned a0 = cpk[qi][2 * kk][0], b0 = cpk[qi][2 * kk + 1][0];
        unsigned a1 = cpk[qi][2 * kk][1], b1 = cpk[qi][2 * kk + 1][1];
        asm("v_permlane32_swap_b32 %0, %1" : "+v"(a0), "+v"(b0));
        asm("v_permlane16_swap_b32 %0, %1" : "+v"(a0), "+v"(b0));
        asm("v_permlane32_swap_b32 %0, %1" : "+v"(a1), "+v"(b1));
        asm("v_permlane16_swap_b32 %0, %1" : "+v"(a1), "+v"(b1));
        union { unsigned u[4]; bf16x8 v; } tmp;
        tmp.u[0] = a0; tmp.u[1] = a1; tmp.u[2] = b0; tmp.u[3] = b1;
        pf[qi][kk] = tmp.v;
      }

    __builtin_amdgcn_s_setprio(1);
    acc_l[0] = __builtin_amdgcn_mfma_f32_16x16x32_bf16(pf[0][0], onesf, acc_l[0], 0, 0, 0);
    acc_l[0] = __builtin_amdgcn_mfma_f32_16x16x32_bf16(pf[0][1], onesf, acc_l[0], 0, 0, 0);
    acc_l[1] = __builtin_amdgcn_mfma_f32_16x16x32_bf16(pf[1][0], onesf, acc_l[1], 0, 0, 0);
    acc_l[1] = __builtin_amdgcn_mfma_f32_16x16x32_bf16(pf[1][1], onesf, acc_l[1], 0, 0, 0);
#pragma unroll
    for (int ni = 0; ni < 4; ++ni) {
      bf16x8 vf0 = *(const bf16x8*)(Vb + (ni * 16 + lr) * 64 + ((lg ^ sx) * 8));
      bf16x8 vf1 = *(const bf16x8*)(Vb + (ni * 16 + lr) * 64 + (((4 + lg) ^ sx) * 8));
      acc[ni][0] = __builtin_amdgcn_mfma_f32_16x16x32_bf16(pf[0][0], vf0, acc[ni][0], 0, 0, 0);
      acc[ni][0] = __builtin_amdgcn_mfma_f32_16x16x32_bf16(pf[0][1], vf1, acc[ni][0], 0, 0, 0);
      acc[ni][1] = __builtin_amdgcn_mfma_f32_16x16x32_bf16(pf[1][0], vf0, acc[ni][1], 0, 0, 0);
      acc[ni][1] = __builtin_amdgcn_mfma_f32_16x16x32_bf16(pf[1][1], vf1, acc[ni][1], 0, 0, 0);
    }
    __builtin_amdgcn_s_setprio(0);
  }
#undef STAGE

  const int b_ = bh >> 4, hh = bh & 15;
#pragma unroll
  for (int qi = 0; qi < 2; ++qi) {
#pragma unroll
    for (int r = 0; r < 4; ++r) {
      float inv = 1.0f / acc_l[qi][r];
      int s = qb + qi * 16 + lg * 4 + r;
#pragma unroll
      for (int ni = 0; ni < 4; ++ni)
        aout[((size_t)(b_ * S_LEN + s)) * DM + hh * DK + ni * 16 + lr] =
            f2bf(acc[ni][qi][r] * inv);
    }
  }
}

extern "C" void kernel_launch(void* const* d_in, const int* in_sizes, int n_in,
                              void* d_out, int out_size, void* d_ws, size_t ws_size,
                              hipStream_t stream) {
  (void)in_sizes; (void)n_in; (void)out_size; (void)ws_size;
  const float* q  = (const float*)d_in[0];
  const float* k  = (const float*)d_in[1];
  const float* v  = (const float*)d_in[2];
  const float* Wq = (const float*)d_in[3];
  const float* bq = (const float*)d_in[4];
  const float* Wk = (const float*)d_in[5];
  const float* bk = (const float*)d_in[6];
  const float* Wv = (const float*)d_in[7];
  const float* bv = (const float*)d_in[8];
  const float* Wo = (const float*)d_in[9];
  const float* bo = (const float*)d_in[10];
  float* out = (float*)d_out;

  // ws (u16 units): qws|kws|vws (8M each) | aws (8M) | wb (4 x 1M) => 36700160 u16 = 73.4 MB
  u16* qws = (u16*)d_ws;
  u16* kws = qws + (size_t)8388608;
  u16* vws = kws + (size_t)8388608;
  u16* aws = vws + (size_t)8388608;   // attn output bf16
  u16* wb  = aws + (size_t)8388608;   // Wq(scaled)|Wk|Wv|Wo bf16

  conv_w<<<dim3(4096), dim3(256), 0, stream>>>(Wq, Wk, Wv, Wo, wb);

  proj_gemm<<<dim3(64, 8, 3), dim3(256), 0, stream>>>(q, k, v, wb, bq, bk, bv,
                                                      qws, kws, vws);

  attn_kernel<<<dim3(1024), dim3(256), 0, stream>>>(qws, kws, vws, aws);

  oproj_gemm<<<dim3(64, 8), dim3(256), 0, stream>>>(aws, wb + 3145728, bo, out);
}

// Round 23
// 191.660 us; speedup vs baseline: 1.0420x; 1.0420x over previous
//
#include <hip/hip_runtime.h>

typedef short bf16x8 __attribute__((ext_vector_type(8)));
typedef float f32x4 __attribute__((ext_vector_type(4)));
typedef unsigned short u16;

#define S_LEN 2048
#define DM 1024
#define NH 16
#define DK 64
#define BHD ((size_t)S_LEN * DK) /* elements per (b,h) head = 131072 */

// Q projection pre-scale: 1/sqrt(dk) * log2(e). Folded into the Wq conversion.
#define QSCALE 0.18033688011112042f

static __device__ __forceinline__ u16 f2bf(float f) {
  union { float f; unsigned u; } x; x.f = f;
  unsigned r = x.u + 0x7FFFu + ((x.u >> 16) & 1u);
  return (u16)(r >> 16);
}

// async global->LDS, 16B per lane, linear LDS dest (wave-uniform base + lane*16)
static __device__ __forceinline__ void gload_lds16(const u16* g, u16* l) {
  __builtin_amdgcn_global_load_lds(
      (const __attribute__((address_space(1))) unsigned int*)g,
      (__attribute__((address_space(3))) unsigned int*)l, 16, 0, 0);
}

// ---------------- f32 -> bf16 conversion for the 4 weight matrices only -------------------
__global__ __launch_bounds__(256) void conv_w(
    const float* __restrict__ Wq, const float* __restrict__ Wk,
    const float* __restrict__ Wv, const float* __restrict__ Wo,
    u16* __restrict__ wb) {
  const int b = blockIdx.x;
  const int wsel = b >> 10;
  const float* s = (wsel == 0) ? Wq : (wsel == 1) ? Wk : (wsel == 2) ? Wv : Wo;
  const float sc = (wsel == 0) ? QSCALE : 1.0f;
  u16* d = wb + (size_t)wsel * 1048576;
  int i = (b & 1023) * 256 + threadIdx.x;
  float4 vv = ((const float4*)s)[i];
  ushort4 h;
  h.x = f2bf(vv.x * sc); h.y = f2bf(vv.y * sc);
  h.z = f2bf(vv.z * sc); h.w = f2bf(vv.w * sc);
  ((ushort4*)d)[i] = h;
}

// ---- bf16 tile staging via global_load_lds: [128 rows][64 cols], pre-swizzled source ----
// (R18/R22 lesson: this 64-col conflict-free layout beats BK=32 variants decisively.)
#define GSTAGE(DST, SRC)                                                          \
  {                                                                               \
    _Pragma("unroll") for (int j = 0; j < 4; ++j) {                               \
      gload_lds16((SRC) + (size_t)(j * 32 + (w << 3) + (l >> 3)) * 1024 +         \
                      (size_t)(((l & 7) ^ (l >> 3)) * 8),                         \
                  (DST) + (j * 256 + w * 64) * 8);                                \
    }                                                                             \
  }

// ---- f32 A-tile reg-staging: load to regs, later cvt+ds_write (G15 async split) ---------
#define ASTAGE_LOAD(R, SRCF, K0)                                                  \
  {                                                                               \
    _Pragma("unroll") for (int j = 0; j < 4; ++j) {                               \
      const int r_ = j * 32 + (t >> 3);                                           \
      const int g_ = (t & 7) ^ (r_ & 7);                                          \
      const float* p_ = (SRCF) + (size_t)(m0 + r_) * 1024 + (K0) + g_ * 8;        \
      R[j][0] = *(const float4*)(p_);                                             \
      R[j][1] = *(const float4*)(p_ + 4);                                         \
    }                                                                             \
  }
#define ASTAGE_WRITE(DST, R)                                                      \
  {                                                                               \
    _Pragma("unroll") for (int j = 0; j < 4; ++j) {                               \
      unsigned u0, u1, u2, u3;                                                    \
      asm("v_cvt_pk_bf16_f32 %0, %1, %2" : "=v"(u0) : "v"(R[j][0].x), "v"(R[j][0].y)); \
      asm("v_cvt_pk_bf16_f32 %0, %1, %2" : "=v"(u1) : "v"(R[j][0].z), "v"(R[j][0].w)); \
      asm("v_cvt_pk_bf16_f32 %0, %1, %2" : "=v"(u2) : "v"(R[j][1].x), "v"(R[j][1].y)); \
      asm("v_cvt_pk_bf16_f32 %0, %1, %2" : "=v"(u3) : "v"(R[j][1].z), "v"(R[j][1].w)); \
      uint4 pk_; pk_.x = u0; pk_.y = u1; pk_.z = u2; pk_.w = u3;                  \
      *(uint4*)((DST) + (size_t)(t + j * 256) * 8) = pk_;                         \
    }                                                                             \
  }

// ---------------- fused QKV projection GEMM: Y = X(f32) @ Wb^T (+ bias*bscale) ------------
// R21 structure (session best). Per-iter top: issue B gload FIRST (async loads get a head
// start over the VALU cvt block), then write A(i+1) (its loads landed during i-1), then
// issue A loads for i+2; all drain under compute(i).
__global__ __launch_bounds__(256) void proj_gemm(
    const float* __restrict__ qf32, const float* __restrict__ kf32,
    const float* __restrict__ vf32, const u16* __restrict__ wb,
    const float* __restrict__ bq, const float* __restrict__ bk, const float* __restrict__ bv,
    u16* __restrict__ qws, u16* __restrict__ kws, u16* __restrict__ vws)
{
  __shared__ u16 Al[2][128 * 64];
  __shared__ u16 Bl[2][128 * 64];
  const int z = blockIdx.z;
  const float* Xf = (z == 0) ? qf32 : (z == 1) ? kf32 : vf32;
  const u16* Wb = wb + (size_t)z * 1048576;
  const float* bias = (z == 0) ? bq : (z == 1) ? bk : bv;
  const float bscale = (z == 0) ? QSCALE : 1.0f;

  const int t = threadIdx.x;
  const int l = t & 63, w = t >> 6;
  const int lr = l & 15, lg = l >> 4;
  const int wm = w >> 1, wn = w & 1;
  const int m0 = blockIdx.x * 128, n0 = blockIdx.y * 128;
  const int sxr = lr & 7;

  f32x4 acc[4][4] = {};
  float4 areg[4][2];

  // prologue: tile 0 staged (write waits vmcnt once), tile 1 loads in flight
  ASTAGE_LOAD(areg, Xf, 0)
  GSTAGE(&Bl[0][0], Wb + (size_t)n0 * 1024)
  ASTAGE_WRITE(&Al[0][0], areg)
  ASTAGE_LOAD(areg, Xf, 64)

  for (int i = 0; i < 16; ++i) {
    __syncthreads();
    if (i < 15) {
      GSTAGE(&Bl[(i + 1) & 1][0], Wb + (size_t)n0 * 1024 + (i + 1) * 64)
      ASTAGE_WRITE(&Al[(i + 1) & 1][0], areg)          // tile i+1 (loads landed during i-1)
    }
    if (i < 14) ASTAGE_LOAD(areg, Xf, (i + 2) * 64)    // tile i+2 flies under compute(i)

    const u16* Ab_ = &Al[i & 1][0];
    const u16* Bb_ = &Bl[i & 1][0];

    bf16x8 a[4][2], b[4][2];
#pragma unroll
    for (int mi = 0; mi < 4; ++mi) {
      const u16* rp = Ab_ + (wm * 64 + mi * 16 + lr) * 64;
      a[mi][0] = *(const bf16x8*)(rp + ((lg ^ sxr) * 8));
      a[mi][1] = *(const bf16x8*)(rp + (((4 + lg) ^ sxr) * 8));
    }
#pragma unroll
    for (int ni = 0; ni < 4; ++ni) {
      const u16* rp = Bb_ + (wn * 64 + ni * 16 + lr) * 64;
      b[ni][0] = *(const bf16x8*)(rp + ((lg ^ sxr) * 8));
      b[ni][1] = *(const bf16x8*)(rp + (((4 + lg) ^ sxr) * 8));
    }
    __builtin_amdgcn_s_setprio(1);
#pragma unroll
    for (int mi = 0; mi < 4; ++mi)
#pragma unroll
      for (int ni = 0; ni < 4; ++ni) {
        acc[mi][ni] = __builtin_amdgcn_mfma_f32_16x16x32_bf16(a[mi][0], b[ni][0], acc[mi][ni], 0, 0, 0);
        acc[mi][ni] = __builtin_amdgcn_mfma_f32_16x16x32_bf16(a[mi][1], b[ni][1], acc[mi][ni], 0, 0, 0);
      }
    __builtin_amdgcn_s_setprio(0);
  }

#pragma unroll
  for (int mi = 0; mi < 4; ++mi) {
#pragma unroll
    for (int ni = 0; ni < 4; ++ni) {
#pragma unroll
      for (int r = 0; r < 4; ++r) {
        int m = m0 + wm * 64 + mi * 16 + lg * 4 + r;
        int n = n0 + wn * 64 + ni * 16 + lr;
        float y = acc[mi][ni][r] + bias[n] * bscale;
        u16 h = f2bf(y);
        int b_ = m >> 11, s = m & 2047, hh = n >> 6, d = n & 63;
        size_t head = (size_t)(b_ * NH + hh);
        if (z == 0)      qws[head * BHD + (size_t)s * DK + d] = h;
        else if (z == 1) kws[head * BHD + (size_t)s * DK + d] = h;
        else             vws[head * BHD + (size_t)d * S_LEN + s] = h;  // V transposed
      }
    }
  }
}

// ---------------- output projection GEMM: out = Ab(bf16) @ Wob^T + bo (fp32 out) ----------
__global__ __launch_bounds__(256) void oproj_gemm(
    const u16* __restrict__ Ab, const u16* __restrict__ Wob,
    const float* __restrict__ bo, float* __restrict__ out)
{
  __shared__ u16 Al[2][128 * 64];
  __shared__ u16 Bl[2][128 * 64];
  const int t = threadIdx.x;
  const int l = t & 63, w = t >> 6;
  const int lr = l & 15, lg = l >> 4;
  const int wm = w >> 1, wn = w & 1;
  const int m0 = blockIdx.x * 128, n0 = blockIdx.y * 128;
  const int sxr = lr & 7;

  f32x4 acc[4][4] = {};

  GSTAGE(&Al[0][0], Ab + (size_t)m0 * 1024)
  GSTAGE(&Bl[0][0], Wob + (size_t)n0 * 1024)

  for (int i = 0; i < 16; ++i) {
    __syncthreads();
    if (i < 15) {
      GSTAGE(&Al[(i + 1) & 1][0], Ab + (size_t)m0 * 1024 + (i + 1) * 64)
      GSTAGE(&Bl[(i + 1) & 1][0], Wob + (size_t)n0 * 1024 + (i + 1) * 64)
    }
    const u16* Ab_ = &Al[i & 1][0];
    const u16* Bb_ = &Bl[i & 1][0];

    bf16x8 a[4][2], b[4][2];
#pragma unroll
    for (int mi = 0; mi < 4; ++mi) {
      const u16* rp = Ab_ + (wm * 64 + mi * 16 + lr) * 64;
      a[mi][0] = *(const bf16x8*)(rp + ((lg ^ sxr) * 8));
      a[mi][1] = *(const bf16x8*)(rp + (((4 + lg) ^ sxr) * 8));
    }
#pragma unroll
    for (int ni = 0; ni < 4; ++ni) {
      const u16* rp = Bb_ + (wn * 64 + ni * 16 + lr) * 64;
      b[ni][0] = *(const bf16x8*)(rp + ((lg ^ sxr) * 8));
      b[ni][1] = *(const bf16x8*)(rp + (((4 + lg) ^ sxr) * 8));
    }
    __builtin_amdgcn_s_setprio(1);
#pragma unroll
    for (int mi = 0; mi < 4; ++mi)
#pragma unroll
      for (int ni = 0; ni < 4; ++ni) {
        acc[mi][ni] = __builtin_amdgcn_mfma_f32_16x16x32_bf16(a[mi][0], b[ni][0], acc[mi][ni], 0, 0, 0);
        acc[mi][ni] = __builtin_amdgcn_mfma_f32_16x16x32_bf16(a[mi][1], b[ni][1], acc[mi][ni], 0, 0, 0);
      }
    __builtin_amdgcn_s_setprio(0);
  }

#pragma unroll
  for (int mi = 0; mi < 4; ++mi) {
#pragma unroll
    for (int ni = 0; ni < 4; ++ni) {
#pragma unroll
      for (int r = 0; r < 4; ++r) {
        int m = m0 + wm * 64 + mi * 16 + lg * 4 + r;
        int n = n0 + wn * 64 + ni * 16 + lr;
        out[(size_t)m * DM + n] = acc[mi][ni][r] + bo[n];
      }
    }
  }
}

// ---------------- flash attention (unchanged from R16 — validated) -------------------------
__global__ __launch_bounds__(256, 4) void attn_kernel(
    const u16* __restrict__ qh, const u16* __restrict__ kh,
    const u16* __restrict__ vt, u16* __restrict__ aout)
{
  __shared__ u16 KT[2][64 * 64];
  __shared__ u16 VT[2][64 * 64];

  const int t = threadIdx.x;
  const int l = t & 63, w = t >> 6;      // 4 waves
  const int lr = l & 15, lg = l >> 4;

  const int bid = blockIdx.x;
  const int logical = (bid & 7) * 128 + (bid >> 3);
  const int bh = logical >> 4;               // 16 blocks per head
  const int qb = (logical & 15) * 128 + w * 32;

  const u16* qp = qh + (size_t)bh * BHD;
  const u16* kp = kh + (size_t)bh * BHD;
  const u16* vp = vt + (size_t)bh * BHD;
  const int sx = lr & 7;

  const int srow = t >> 3;                   // 0..31
  const int scolS = (t & 7) ^ (srow & 7);    // inverse-swizzled source 16B-chunk

  bf16x8 qf[2][2];
#pragma unroll
  for (int qi = 0; qi < 2; ++qi)
#pragma unroll
    for (int c = 0; c < 2; ++c)
      qf[qi][c] = *(const bf16x8*)(qp + (size_t)(qb + qi * 16 + lr) * DK + c * 32 + lg * 8);

  bf16x8 onesf;
#pragma unroll
  for (int e = 0; e < 8; ++e) onesf[e] = (short)0x3F80;

  f32x4 acc[4][2] = {};
  f32x4 acc_l[2] = {};

#define STAGE(B, KV)                                                                  \
  {                                                                                   \
    _Pragma("unroll") for (int j = 0; j < 2; ++j) {                                   \
      gload_lds16(kp + (size_t)((KV) + j * 32 + srow) * DK + scolS * 8,               \
                  &KT[B][j * 2048 + w * 512]);                                        \
      gload_lds16(vp + (size_t)(j * 32 + srow) * S_LEN + (KV) + scolS * 8,            \
                  &VT[B][j * 2048 + w * 512]);                                        \
    }                                                                                 \
  }

  STAGE(0, 0)

  for (int i = 0; i < 32; ++i) {
    __syncthreads();
    if (i < 31) STAGE((i + 1) & 1, (i + 1) * 64)

    const u16* Kb = &KT[i & 1][0];
    const u16* Vb = &VT[i & 1][0];

    f32x4 sc[4][2] = {};
    __builtin_amdgcn_s_setprio(1);
#pragma unroll
    for (int ct = 0; ct < 4; ++ct) {
      bf16x8 k0 = *(const bf16x8*)(Kb + (ct * 16 + lr) * 64 + ((lg ^ sx) * 8));
      bf16x8 k1 = *(const bf16x8*)(Kb + (ct * 16 + lr) * 64 + (((4 + lg) ^ sx) * 8));
      sc[ct][0] = __builtin_amdgcn_mfma_f32_16x16x32_bf16(k0, qf[0][0], sc[ct][0], 0, 0, 0);
      sc[ct][0] = __builtin_amdgcn_mfma_f32_16x16x32_bf16(k1, qf[0][1], sc[ct][0], 0, 0, 0);
      sc[ct][1] = __builtin_amdgcn_mfma_f32_16x16x32_bf16(k0, qf[1][0], sc[ct][1], 0, 0, 0);
      sc[ct][1] = __builtin_amdgcn_mfma_f32_16x16x32_bf16(k1, qf[1][1], sc[ct][1], 0, 0, 0);
    }
    __builtin_amdgcn_s_setprio(0);

    unsigned cpk[2][4][2];
#pragma unroll
    for (int qi = 0; qi < 2; ++qi) {
#pragma unroll
      for (int ct = 0; ct < 4; ++ct) {
        float p0 = __builtin_amdgcn_exp2f(sc[ct][qi][0]);
        float p1 = __builtin_amdgcn_exp2f(sc[ct][qi][1]);
        float p2 = __builtin_amdgcn_exp2f(sc[ct][qi][2]);
        float p3 = __builtin_amdgcn_exp2f(sc[ct][qi][3]);
        asm("v_cvt_pk_bf16_f32 %0, %1, %2" : "=v"(cpk[qi][ct][0]) : "v"(p0), "v"(p1));
        asm("v_cvt_pk_bf16_f32 %0, %1, %2" : "=v"(cpk[qi][ct][1]) : "v"(p2), "v"(p3));
      }
    }

    bf16x8 pf[2][2];
#pragma unroll
    for (int qi = 0; qi < 2; ++qi)
#pragma unroll
      for (int kk = 0; kk < 2; ++kk) {
        unsigned a0 = cpk[qi][2 * kk][0], b0 = cpk[qi][2 * kk + 1][0];
        unsigned a1 = cpk[qi][2 * kk][1], b1 = cpk[qi][2 * kk + 1][1];
        asm("v_permlane32_swap_b32 %0, %1" : "+v"(a0), "+v"(b0));
        asm("v_permlane16_swap_b32 %0, %1" : "+v"(a0), "+v"(b0));
        asm("v_permlane32_swap_b32 %0, %1" : "+v"(a1), "+v"(b1));
        asm("v_permlane16_swap_b32 %0, %1" : "+v"(a1), "+v"(b1));
        union { unsigned u[4]; bf16x8 v; } tmp;
        tmp.u[0] = a0; tmp.u[1] = a1; tmp.u[2] = b0; tmp.u[3] = b1;
        pf[qi][kk] = tmp.v;
      }

    __builtin_amdgcn_s_setprio(1);
    acc_l[0] = __builtin_amdgcn_mfma_f32_16x16x32_bf16(pf[0][0], onesf, acc_l[0], 0, 0, 0);
    acc_l[0] = __builtin_amdgcn_mfma_f32_16x16x32_bf16(pf[0][1], onesf, acc_l[0], 0, 0, 0);
    acc_l[1] = __builtin_amdgcn_mfma_f32_16x16x32_bf16(pf[1][0], onesf, acc_l[1], 0, 0, 0);
    acc_l[1] = __builtin_amdgcn_mfma_f32_16x16x32_bf16(pf[1][1], onesf, acc_l[1], 0, 0, 0);
#pragma unroll
    for (int ni = 0; ni < 4; ++ni) {
      bf16x8 vf0 = *(const bf16x8*)(Vb + (ni * 16 + lr) * 64 + ((lg ^ sx) * 8));
      bf16x8 vf1 = *(const bf16x8*)(Vb + (ni * 16 + lr) * 64 + (((4 + lg) ^ sx) * 8));
      acc[ni][0] = __builtin_amdgcn_mfma_f32_16x16x32_bf16(pf[0][0], vf0, acc[ni][0], 0, 0, 0);
      acc[ni][0] = __builtin_amdgcn_mfma_f32_16x16x32_bf16(pf[0][1], vf1, acc[ni][0], 0, 0, 0);
      acc[ni][1] = __builtin_amdgcn_mfma_f32_16x16x32_bf16(pf[1][0], vf0, acc[ni][1], 0, 0, 0);
      acc[ni][1] = __builtin_amdgcn_mfma_f32_16x16x32_bf16(pf[1][1], vf1, acc[ni][1], 0, 0, 0);
    }
    __builtin_amdgcn_s_setprio(0);
  }
#undef STAGE

  const int b_ = bh >> 4, hh = bh & 15;
#pragma unroll
  for (int qi = 0; qi < 2; ++qi) {
#pragma unroll
    for (int r = 0; r < 4; ++r) {
      float inv = 1.0f / acc_l[qi][r];
      int s = qb + qi * 16 + lg * 4 + r;
#pragma unroll
      for (int ni = 0; ni < 4; ++ni)
        aout[((size_t)(b_ * S_LEN + s)) * DM + hh * DK + ni * 16 + lr] =
            f2bf(acc[ni][qi][r] * inv);
    }
  }
}

extern "C" void kernel_launch(void* const* d_in, const int* in_sizes, int n_in,
                              void* d_out, int out_size, void* d_ws, size_t ws_size,
                              hipStream_t stream) {
  (void)in_sizes; (void)n_in; (void)out_size; (void)ws_size;
  const float* q  = (const float*)d_in[0];
  const float* k  = (const float*)d_in[1];
  const float* v  = (const float*)d_in[2];
  const float* Wq = (const float*)d_in[3];
  const float* bq = (const float*)d_in[4];
  const float* Wk = (const float*)d_in[5];
  const float* bk = (const float*)d_in[6];
  const float* Wv = (const float*)d_in[7];
  const float* bv = (const float*)d_in[8];
  const float* Wo = (const float*)d_in[9];
  const float* bo = (const float*)d_in[10];
  float* out = (float*)d_out;

  // ws (u16 units): qws|kws|vws (8M each) | aws (8M) | wb (4 x 1M) => 36700160 u16 = 73.4 MB
  u16* qws = (u16*)d_ws;
  u16* kws = qws + (size_t)8388608;
  u16* vws = kws + (size_t)8388608;
  u16* aws = vws + (size_t)8388608;   // attn output bf16
  u16* wb  = aws + (size_t)8388608;   // Wq(scaled)|Wk|Wv|Wo bf16

  conv_w<<<dim3(4096), dim3(256), 0, stream>>>(Wq, Wk, Wv, Wo, wb);

  proj_gemm<<<dim3(64, 8, 3), dim3(256), 0, stream>>>(q, k, v, wb, bq, bk, bv,
                                                      qws, kws, vws);

  attn_kernel<<<dim3(1024), dim3(256), 0, stream>>>(qws, kws, vws, aws);

  oproj_gemm<<<dim3(64, 8), dim3(256), 0, stream>>>(aws, wb + 3145728, bo, out);
}

// Round 24
// 187.242 us; speedup vs baseline: 1.0666x; 1.0236x over previous
//
#include <hip/hip_runtime.h>

typedef short bf16x8 __attribute__((ext_vector_type(8)));
typedef float f32x4 __attribute__((ext_vector_type(4)));
typedef unsigned short u16;

#define S_LEN 2048
#define DM 1024
#define NH 16
#define DK 64
#define BHD ((size_t)S_LEN * DK) /* elements per (b,h) head = 131072 */

// Q projection pre-scale: 1/sqrt(dk) * log2(e). Folded into the Wq conversion.
#define QSCALE 0.18033688011112042f

static __device__ __forceinline__ u16 f2bf(float f) {
  union { float f; unsigned u; } x; x.f = f;
  unsigned r = x.u + 0x7FFFu + ((x.u >> 16) & 1u);
  return (u16)(r >> 16);
}

// async global->LDS, 16B per lane, linear LDS dest (wave-uniform base + lane*16)
static __device__ __forceinline__ void gload_lds16(const u16* g, u16* l) {
  __builtin_amdgcn_global_load_lds(
      (const __attribute__((address_space(1))) unsigned int*)g,
      (__attribute__((address_space(3))) unsigned int*)l, 16, 0, 0);
}

// ---------------- f32 -> bf16 conversion for the 4 weight matrices only -------------------
__global__ __launch_bounds__(256) void conv_w(
    const float* __restrict__ Wq, const float* __restrict__ Wk,
    const float* __restrict__ Wv, const float* __restrict__ Wo,
    u16* __restrict__ wb) {
  const int b = blockIdx.x;
  const int wsel = b >> 10;
  const float* s = (wsel == 0) ? Wq : (wsel == 1) ? Wk : (wsel == 2) ? Wv : Wo;
  const float sc = (wsel == 0) ? QSCALE : 1.0f;
  u16* d = wb + (size_t)wsel * 1048576;
  int i = (b & 1023) * 256 + threadIdx.x;
  float4 vv = ((const float4*)s)[i];
  ushort4 h;
  h.x = f2bf(vv.x * sc); h.y = f2bf(vv.y * sc);
  h.z = f2bf(vv.z * sc); h.w = f2bf(vv.w * sc);
  ((ushort4*)d)[i] = h;
}

// ---- bf16 tile staging via global_load_lds (256-thread form, used by oproj) -------------
#define GSTAGE(DST, SRC)                                                          \
  {                                                                               \
    _Pragma("unroll") for (int j = 0; j < 4; ++j) {                               \
      gload_lds16((SRC) + (size_t)(j * 32 + (w << 3) + (l >> 3)) * 1024 +         \
                      (size_t)(((l & 7) ^ (l >> 3)) * 8),                         \
                  (DST) + (j * 256 + w * 64) * 8);                                \
    }                                                                             \
  }

// ---- 512-thread (8-wave) staging forms for proj ------------------------------------------
// Tile [128 rows][64 u16]; stored 16B-pos p holds global chunk p^(row&7).
#define GSTAGE8(DST, SRC)                                                         \
  {                                                                               \
    _Pragma("unroll") for (int j = 0; j < 2; ++j) {                               \
      gload_lds16((SRC) + (size_t)(j * 64 + (w << 3) + (l >> 3)) * 1024 +         \
                      (size_t)(((l & 7) ^ (l >> 3)) * 8),                         \
                  (DST) + (j * 512 + w * 64) * 8);                                \
    }                                                                             \
  }
#define ASTAGE_LOAD8(R, SRCF, K0)                                                 \
  {                                                                               \
    _Pragma("unroll") for (int j = 0; j < 2; ++j) {                               \
      const int r_ = j * 64 + (t >> 3);                                           \
      const int g_ = (t & 7) ^ (r_ & 7);                                          \
      const float* p_ = (SRCF) + (size_t)(m0 + r_) * 1024 + (K0) + g_ * 8;        \
      R[j][0] = *(const float4*)(p_);                                             \
      R[j][1] = *(const float4*)(p_ + 4);                                         \
    }                                                                             \
  }
#define ASTAGE_WRITE8(DST, R)                                                     \
  {                                                                               \
    _Pragma("unroll") for (int j = 0; j < 2; ++j) {                               \
      unsigned u0, u1, u2, u3;                                                    \
      asm("v_cvt_pk_bf16_f32 %0, %1, %2" : "=v"(u0) : "v"(R[j][0].x), "v"(R[j][0].y)); \
      asm("v_cvt_pk_bf16_f32 %0, %1, %2" : "=v"(u1) : "v"(R[j][0].z), "v"(R[j][0].w)); \
      asm("v_cvt_pk_bf16_f32 %0, %1, %2" : "=v"(u2) : "v"(R[j][1].x), "v"(R[j][1].y)); \
      asm("v_cvt_pk_bf16_f32 %0, %1, %2" : "=v"(u3) : "v"(R[j][1].z), "v"(R[j][1].w)); \
      uint4 pk_; pk_.x = u0; pk_.y = u1; pk_.z = u2; pk_.w = u3;                  \
      *(uint4*)((DST) + (size_t)(t + j * 512) * 8) = pk_;                         \
    }                                                                             \
  }

// ---------------- fused QKV projection GEMM: Y = X(f32) @ Wb^T (+ bias*bscale) ------------
// 8 waves x 512 threads, 128x128 tile, each wave owns 64x32 (acc 4x2).
// R23 was 2 waves/SIMD (stall-bound, MfmaUtil 17%); halved per-wave state doubles
// co-resident waves to 4/SIMD at the same 64KB dbuf LDS. A-pipeline = R21 write-at-top.
__global__ __launch_bounds__(512, 4) void proj_gemm(
    const float* __restrict__ qf32, const float* __restrict__ kf32,
    const float* __restrict__ vf32, const u16* __restrict__ wb,
    const float* __restrict__ bq, const float* __restrict__ bk, const float* __restrict__ bv,
    u16* __restrict__ qws, u16* __restrict__ kws, u16* __restrict__ vws)
{
  __shared__ u16 Al[2][128 * 64];
  __shared__ u16 Bl[2][128 * 64];
  const int z = blockIdx.z;
  const float* Xf = (z == 0) ? qf32 : (z == 1) ? kf32 : vf32;
  const u16* Wb = wb + (size_t)z * 1048576;
  const float* bias = (z == 0) ? bq : (z == 1) ? bk : bv;
  const float bscale = (z == 0) ? QSCALE : 1.0f;

  const int t = threadIdx.x;
  const int l = t & 63, w = t >> 6;        // 8 waves
  const int lr = l & 15, lg = l >> 4;
  const int wm = w >> 2, wn = w & 3;       // 2 x 4 wave grid
  const int m0 = blockIdx.x * 128, n0 = blockIdx.y * 128;
  const int sxr = lr & 7;

  f32x4 acc[4][2] = {};
  float4 areg[2][2];

  // prologue: tile 0 staged (write waits vmcnt once), tile 1 loads in flight
  ASTAGE_LOAD8(areg, Xf, 0)
  GSTAGE8(&Bl[0][0], Wb + (size_t)n0 * 1024)
  ASTAGE_WRITE8(&Al[0][0], areg)
  ASTAGE_LOAD8(areg, Xf, 64)

  for (int i = 0; i < 16; ++i) {
    __syncthreads();
    if (i < 15) {
      GSTAGE8(&Bl[(i + 1) & 1][0], Wb + (size_t)n0 * 1024 + (i + 1) * 64)
      ASTAGE_WRITE8(&Al[(i + 1) & 1][0], areg)         // tile i+1 (loads landed during i-1)
    }
    if (i < 14) ASTAGE_LOAD8(areg, Xf, (i + 2) * 64)   // tile i+2 flies under compute(i)

    const u16* Ab_ = &Al[i & 1][0];
    const u16* Bb_ = &Bl[i & 1][0];

    bf16x8 a[4][2], b[2][2];
#pragma unroll
    for (int mi = 0; mi < 4; ++mi) {
      const u16* rp = Ab_ + (wm * 64 + mi * 16 + lr) * 64;
      a[mi][0] = *(const bf16x8*)(rp + ((lg ^ sxr) * 8));
      a[mi][1] = *(const bf16x8*)(rp + (((4 + lg) ^ sxr) * 8));
    }
#pragma unroll
    for (int ni = 0; ni < 2; ++ni) {
      const u16* rp = Bb_ + (wn * 32 + ni * 16 + lr) * 64;
      b[ni][0] = *(const bf16x8*)(rp + ((lg ^ sxr) * 8));
      b[ni][1] = *(const bf16x8*)(rp + (((4 + lg) ^ sxr) * 8));
    }
    __builtin_amdgcn_s_setprio(1);
#pragma unroll
    for (int mi = 0; mi < 4; ++mi)
#pragma unroll
      for (int ni = 0; ni < 2; ++ni) {
        acc[mi][ni] = __builtin_amdgcn_mfma_f32_16x16x32_bf16(a[mi][0], b[ni][0], acc[mi][ni], 0, 0, 0);
        acc[mi][ni] = __builtin_amdgcn_mfma_f32_16x16x32_bf16(a[mi][1], b[ni][1], acc[mi][ni], 0, 0, 0);
      }
    __builtin_amdgcn_s_setprio(0);
  }

#pragma unroll
  for (int mi = 0; mi < 4; ++mi) {
#pragma unroll
    for (int ni = 0; ni < 2; ++ni) {
#pragma unroll
      for (int r = 0; r < 4; ++r) {
        int m = m0 + wm * 64 + mi * 16 + lg * 4 + r;
        int n = n0 + wn * 32 + ni * 16 + lr;
        float y = acc[mi][ni][r] + bias[n] * bscale;
        u16 h = f2bf(y);
        int b_ = m >> 11, s = m & 2047, hh = n >> 6, d = n & 63;
        size_t head = (size_t)(b_ * NH + hh);
        if (z == 0)      qws[head * BHD + (size_t)s * DK + d] = h;
        else if (z == 1) kws[head * BHD + (size_t)s * DK + d] = h;
        else             vws[head * BHD + (size_t)d * S_LEN + s] = h;  // V transposed
      }
    }
  }
}

// ---------------- output projection GEMM: out = Ab(bf16) @ Wob^T + bo (fp32 out) ----------
// R17/R21 256-thread double-buffered structure (unchanged — proven).
__global__ __launch_bounds__(256) void oproj_gemm(
    const u16* __restrict__ Ab, const u16* __restrict__ Wob,
    const float* __restrict__ bo, float* __restrict__ out)
{
  __shared__ u16 Al[2][128 * 64];
  __shared__ u16 Bl[2][128 * 64];
  const int t = threadIdx.x;
  const int l = t & 63, w = t >> 6;
  const int lr = l & 15, lg = l >> 4;
  const int wm = w >> 1, wn = w & 1;
  const int m0 = blockIdx.x * 128, n0 = blockIdx.y * 128;
  const int sxr = lr & 7;

  f32x4 acc[4][4] = {};

  GSTAGE(&Al[0][0], Ab + (size_t)m0 * 1024)
  GSTAGE(&Bl[0][0], Wob + (size_t)n0 * 1024)

  for (int i = 0; i < 16; ++i) {
    __syncthreads();
    if (i < 15) {
      GSTAGE(&Al[(i + 1) & 1][0], Ab + (size_t)m0 * 1024 + (i + 1) * 64)
      GSTAGE(&Bl[(i + 1) & 1][0], Wob + (size_t)n0 * 1024 + (i + 1) * 64)
    }
    const u16* Ab_ = &Al[i & 1][0];
    const u16* Bb_ = &Bl[i & 1][0];

    bf16x8 a[4][2], b[4][2];
#pragma unroll
    for (int mi = 0; mi < 4; ++mi) {
      const u16* rp = Ab_ + (wm * 64 + mi * 16 + lr) * 64;
      a[mi][0] = *(const bf16x8*)(rp + ((lg ^ sxr) * 8));
      a[mi][1] = *(const bf16x8*)(rp + (((4 + lg) ^ sxr) * 8));
    }
#pragma unroll
    for (int ni = 0; ni < 4; ++ni) {
      const u16* rp = Bb_ + (wn * 64 + ni * 16 + lr) * 64;
      b[ni][0] = *(const bf16x8*)(rp + ((lg ^ sxr) * 8));
      b[ni][1] = *(const bf16x8*)(rp + (((4 + lg) ^ sxr) * 8));
    }
    __builtin_amdgcn_s_setprio(1);
#pragma unroll
    for (int mi = 0; mi < 4; ++mi)
#pragma unroll
      for (int ni = 0; ni < 4; ++ni) {
        acc[mi][ni] = __builtin_amdgcn_mfma_f32_16x16x32_bf16(a[mi][0], b[ni][0], acc[mi][ni], 0, 0, 0);
        acc[mi][ni] = __builtin_amdgcn_mfma_f32_16x16x32_bf16(a[mi][1], b[ni][1], acc[mi][ni], 0, 0, 0);
      }
    __builtin_amdgcn_s_setprio(0);
  }

#pragma unroll
  for (int mi = 0; mi < 4; ++mi) {
#pragma unroll
    for (int ni = 0; ni < 4; ++ni) {
#pragma unroll
      for (int r = 0; r < 4; ++r) {
        int m = m0 + wm * 64 + mi * 16 + lg * 4 + r;
        int n = n0 + wn * 64 + ni * 16 + lr;
        out[(size_t)m * DM + n] = acc[mi][ni][r] + bo[n];
      }
    }
  }
}

// ---------------- flash attention (unchanged from R16 — validated) -------------------------
__global__ __launch_bounds__(256, 4) void attn_kernel(
    const u16* __restrict__ qh, const u16* __restrict__ kh,
    const u16* __restrict__ vt, u16* __restrict__ aout)
{
  __shared__ u16 KT[2][64 * 64];
  __shared__ u16 VT[2][64 * 64];

  const int t = threadIdx.x;
  const int l = t & 63, w = t >> 6;      // 4 waves
  const int lr = l & 15, lg = l >> 4;

  const int bid = blockIdx.x;
  const int logical = (bid & 7) * 128 + (bid >> 3);
  const int bh = logical >> 4;               // 16 blocks per head
  const int qb = (logical & 15) * 128 + w * 32;

  const u16* qp = qh + (size_t)bh * BHD;
  const u16* kp = kh + (size_t)bh * BHD;
  const u16* vp = vt + (size_t)bh * BHD;
  const int sx = lr & 7;

  const int srow = t >> 3;                   // 0..31
  const int scolS = (t & 7) ^ (srow & 7);    // inverse-swizzled source 16B-chunk

  bf16x8 qf[2][2];
#pragma unroll
  for (int qi = 0; qi < 2; ++qi)
#pragma unroll
    for (int c = 0; c < 2; ++c)
      qf[qi][c] = *(const bf16x8*)(qp + (size_t)(qb + qi * 16 + lr) * DK + c * 32 + lg * 8);

  bf16x8 onesf;
#pragma unroll
  for (int e = 0; e < 8; ++e) onesf[e] = (short)0x3F80;

  f32x4 acc[4][2] = {};
  f32x4 acc_l[2] = {};

#define STAGE(B, KV)                                                                  \
  {                                                                                   \
    _Pragma("unroll") for (int j = 0; j < 2; ++j) {                                   \
      gload_lds16(kp + (size_t)((KV) + j * 32 + srow) * DK + scolS * 8,               \
                  &KT[B][j * 2048 + w * 512]);                                        \
      gload_lds16(vp + (size_t)(j * 32 + srow) * S_LEN + (KV) + scolS * 8,            \
                  &VT[B][j * 2048 + w * 512]);                                        \
    }                                                                                 \
  }

  STAGE(0, 0)

  for (int i = 0; i < 32; ++i) {
    __syncthreads();
    if (i < 31) STAGE((i + 1) & 1, (i + 1) * 64)

    const u16* Kb = &KT[i & 1][0];
    const u16* Vb = &VT[i & 1][0];

    f32x4 sc[4][2] = {};
    __builtin_amdgcn_s_setprio(1);
#pragma unroll
    for (int ct = 0; ct < 4; ++ct) {
      bf16x8 k0 = *(const bf16x8*)(Kb + (ct * 16 + lr) * 64 + ((lg ^ sx) * 8));
      bf16x8 k1 = *(const bf16x8*)(Kb + (ct * 16 + lr) * 64 + (((4 + lg) ^ sx) * 8));
      sc[ct][0] = __builtin_amdgcn_mfma_f32_16x16x32_bf16(k0, qf[0][0], sc[ct][0], 0, 0, 0);
      sc[ct][0] = __builtin_amdgcn_mfma_f32_16x16x32_bf16(k1, qf[0][1], sc[ct][0], 0, 0, 0);
      sc[ct][1] = __builtin_amdgcn_mfma_f32_16x16x32_bf16(k0, qf[1][0], sc[ct][1], 0, 0, 0);
      sc[ct][1] = __builtin_amdgcn_mfma_f32_16x16x32_bf16(k1, qf[1][1], sc[ct][1], 0, 0, 0);
    }
    __builtin_amdgcn_s_setprio(0);

    unsigned cpk[2][4][2];
#pragma unroll
    for (int qi = 0; qi < 2; ++qi) {
#pragma unroll
      for (int ct = 0; ct < 4; ++ct) {
        float p0 = __builtin_amdgcn_exp2f(sc[ct][qi][0]);
        float p1 = __builtin_amdgcn_exp2f(sc[ct][qi][1]);
        float p2 = __builtin_amdgcn_exp2f(sc[ct][qi][2]);
        float p3 = __builtin_amdgcn_exp2f(sc[ct][qi][3]);
        asm("v_cvt_pk_bf16_f32 %0, %1, %2" : "=v"(cpk[qi][ct][0]) : "v"(p0), "v"(p1));
        asm("v_cvt_pk_bf16_f32 %0, %1, %2" : "=v"(cpk[qi][ct][1]) : "v"(p2), "v"(p3));
      }
    }

    bf16x8 pf[2][2];
#pragma unroll
    for (int qi = 0; qi < 2; ++qi)
#pragma unroll
      for (int kk = 0; kk < 2; ++kk) {
        unsigned a0 = cpk[qi][2 * kk][0], b0 = cpk[qi][2 * kk + 1][0];
        unsigned a1 = cpk[qi][2 * kk][1], b1 = cpk[qi][2 * kk + 1][1];
        asm("v_permlane32_swap_b32 %0, %1" : "+v"(a0), "+v"(b0));
        asm("v_permlane16_swap_b32 %0, %1" : "+v"(a0), "+v"(b0));
        asm("v_permlane32_swap_b32 %0, %1" : "+v"(a1), "+v"(b1));
        asm("v_permlane16_swap_b32 %0, %1" : "+v"(a1), "+v"(b1));
        union { unsigned u[4]; bf16x8 v; } tmp;
        tmp.u[0] = a0; tmp.u[1] = a1; tmp.u[2] = b0; tmp.u[3] = b1;
        pf[qi][kk] = tmp.v;
      }

    __builtin_amdgcn_s_setprio(1);
    acc_l[0] = __builtin_amdgcn_mfma_f32_16x16x32_bf16(pf[0][0], onesf, acc_l[0], 0, 0, 0);
    acc_l[0] = __builtin_amdgcn_mfma_f32_16x16x32_bf16(pf[0][1], onesf, acc_l[0], 0, 0, 0);
    acc_l[1] = __builtin_amdgcn_mfma_f32_16x16x32_bf16(pf[1][0], onesf, acc_l[1], 0, 0, 0);
    acc_l[1] = __builtin_amdgcn_mfma_f32_16x16x32_bf16(pf[1][1], onesf, acc_l[1], 0, 0, 0);
#pragma unroll
    for (int ni = 0; ni < 4; ++ni) {
      bf16x8 vf0 = *(const bf16x8*)(Vb + (ni * 16 + lr) * 64 + ((lg ^ sx) * 8));
      bf16x8 vf1 = *(const bf16x8*)(Vb + (ni * 16 + lr) * 64 + (((4 + lg) ^ sx) * 8));
      acc[ni][0] = __builtin_amdgcn_mfma_f32_16x16x32_bf16(pf[0][0], vf0, acc[ni][0], 0, 0, 0);
      acc[ni][0] = __builtin_amdgcn_mfma_f32_16x16x32_bf16(pf[0][1], vf1, acc[ni][0], 0, 0, 0);
      acc[ni][1] = __builtin_amdgcn_mfma_f32_16x16x32_bf16(pf[1][0], vf0, acc[ni][1], 0, 0, 0);
      acc[ni][1] = __builtin_amdgcn_mfma_f32_16x16x32_bf16(pf[1][1], vf1, acc[ni][1], 0, 0, 0);
    }
    __builtin_amdgcn_s_setprio(0);
  }
#undef STAGE

  const int b_ = bh >> 4, hh = bh & 15;
#pragma unroll
  for (int qi = 0; qi < 2; ++qi) {
#pragma unroll
    for (int r = 0; r < 4; ++r) {
      float inv = 1.0f / acc_l[qi][r];
      int s = qb + qi * 16 + lg * 4 + r;
#pragma unroll
      for (int ni = 0; ni < 4; ++ni)
        aout[((size_t)(b_ * S_LEN + s)) * DM + hh * DK + ni * 16 + lr] =
            f2bf(acc[ni][qi][r] * inv);
    }
  }
}

extern "C" void kernel_launch(void* const* d_in, const int* in_sizes, int n_in,
                              void* d_out, int out_size, void* d_ws, size_t ws_size,
                              hipStream_t stream) {
  (void)in_sizes; (void)n_in; (void)out_size; (void)ws_size;
  const float* q  = (const float*)d_in[0];
  const float* k  = (const float*)d_in[1];
  const float* v  = (const float*)d_in[2];
  const float* Wq = (const float*)d_in[3];
  const float* bq = (const float*)d_in[4];
  const float* Wk = (const float*)d_in[5];
  const float* bk = (const float*)d_in[6];
  const float* Wv = (const float*)d_in[7];
  const float* bv = (const float*)d_in[8];
  const float* Wo = (const float*)d_in[9];
  const float* bo = (const float*)d_in[10];
  float* out = (float*)d_out;

  // ws (u16 units): qws|kws|vws (8M each) | aws (8M) | wb (4 x 1M) => 36700160 u16 = 73.4 MB
  u16* qws = (u16*)d_ws;
  u16* kws = qws + (size_t)8388608;
  u16* vws = kws + (size_t)8388608;
  u16* aws = vws + (size_t)8388608;   // attn output bf16
  u16* wb  = aws + (size_t)8388608;   // Wq(scaled)|Wk|Wv|Wo bf16

  conv_w<<<dim3(4096), dim3(256), 0, stream>>>(Wq, Wk, Wv, Wo, wb);

  proj_gemm<<<dim3(64, 8, 3), dim3(512), 0, stream>>>(q, k, v, wb, bq, bk, bv,
                                                      qws, kws, vws);

  attn_kernel<<<dim3(1024), dim3(256), 0, stream>>>(qws, kws, vws, aws);

  oproj_gemm<<<dim3(64, 8), dim3(256), 0, stream>>>(aws, wb + 3145728, bo, out);
}

// Round 25
// 184.550 us; speedup vs baseline: 1.0822x; 1.0146x over previous
//
#include <hip/hip_runtime.h>

typedef short bf16x8 __attribute__((ext_vector_type(8)));
typedef float f32x4 __attribute__((ext_vector_type(4)));
typedef unsigned short u16;

#define S_LEN 2048
#define DM 1024
#define NH 16
#define DK 64
#define BHD ((size_t)S_LEN * DK) /* elements per (b,h) head = 131072 */

// Q projection pre-scale: 1/sqrt(dk) * log2(e). Folded into the Wq conversion.
#define QSCALE 0.18033688011112042f

static __device__ __forceinline__ u16 f2bf(float f) {
  union { float f; unsigned u; } x; x.f = f;
  unsigned r = x.u + 0x7FFFu + ((x.u >> 16) & 1u);
  return (u16)(r >> 16);
}

// async global->LDS, 16B per lane, linear LDS dest (wave-uniform base + lane*16)
static __device__ __forceinline__ void gload_lds16(const u16* g, u16* l) {
  __builtin_amdgcn_global_load_lds(
      (const __attribute__((address_space(1))) unsigned int*)g,
      (__attribute__((address_space(3))) unsigned int*)l, 16, 0, 0);
}

// ---------------- f32 -> bf16 conversion for the 4 weight matrices only -------------------
__global__ __launch_bounds__(256) void conv_w(
    const float* __restrict__ Wq, const float* __restrict__ Wk,
    const float* __restrict__ Wv, const float* __restrict__ Wo,
    u16* __restrict__ wb) {
  const int b = blockIdx.x;
  const int wsel = b >> 10;
  const float* s = (wsel == 0) ? Wq : (wsel == 1) ? Wk : (wsel == 2) ? Wv : Wo;
  const float sc = (wsel == 0) ? QSCALE : 1.0f;
  u16* d = wb + (size_t)wsel * 1048576;
  int i = (b & 1023) * 256 + threadIdx.x;
  float4 vv = ((const float4*)s)[i];
  ushort4 h;
  h.x = f2bf(vv.x * sc); h.y = f2bf(vv.y * sc);
  h.z = f2bf(vv.z * sc); h.w = f2bf(vv.w * sc);
  ((ushort4*)d)[i] = h;
}

// ---- 512-thread (8-wave) staging: tile [128 rows][64 u16]; pos p holds chunk p^(row&7) --
#define GSTAGE8(DST, SRC)                                                         \
  {                                                                               \
    _Pragma("unroll") for (int j = 0; j < 2; ++j) {                               \
      gload_lds16((SRC) + (size_t)(j * 64 + (w << 3) + (l >> 3)) * 1024 +         \
                      (size_t)(((l & 7) ^ (l >> 3)) * 8),                         \
                  (DST) + (j * 512 + w * 64) * 8);                                \
    }                                                                             \
  }
#define ASTAGE_LOAD8(R, SRCF, K0)                                                 \
  {                                                                               \
    _Pragma("unroll") for (int j = 0; j < 2; ++j) {                               \
      const int r_ = j * 64 + (t >> 3);                                           \
      const int g_ = (t & 7) ^ (r_ & 7);                                          \
      const float* p_ = (SRCF) + (size_t)(m0 + r_) * 1024 + (K0) + g_ * 8;        \
      R[j][0] = *(const float4*)(p_);                                             \
      R[j][1] = *(const float4*)(p_ + 4);                                         \
    }                                                                             \
  }
#define ASTAGE_WRITE8(DST, R)                                                     \
  {                                                                               \
    _Pragma("unroll") for (int j = 0; j < 2; ++j) {                               \
      unsigned u0, u1, u2, u3;                                                    \
      asm("v_cvt_pk_bf16_f32 %0, %1, %2" : "=v"(u0) : "v"(R[j][0].x), "v"(R[j][0].y)); \
      asm("v_cvt_pk_bf16_f32 %0, %1, %2" : "=v"(u1) : "v"(R[j][0].z), "v"(R[j][0].w)); \
      asm("v_cvt_pk_bf16_f32 %0, %1, %2" : "=v"(u2) : "v"(R[j][1].x), "v"(R[j][1].y)); \
      asm("v_cvt_pk_bf16_f32 %0, %1, %2" : "=v"(u3) : "v"(R[j][1].z), "v"(R[j][1].w)); \
      uint4 pk_; pk_.x = u0; pk_.y = u1; pk_.z = u2; pk_.w = u3;                  \
      *(uint4*)((DST) + (size_t)(t + j * 512) * 8) = pk_;                         \
    }                                                                             \
  }

// ---------------- fused QKV projection GEMM: Y = X(f32) @ Wb^T (+ bias*bscale) ------------
// 8 waves x 512 threads, 128x128 tile, each wave owns 64x32 (acc 4x2). (R24-validated)
__global__ __launch_bounds__(512, 4) void proj_gemm(
    const float* __restrict__ qf32, const float* __restrict__ kf32,
    const float* __restrict__ vf32, const u16* __restrict__ wb,
    const float* __restrict__ bq, const float* __restrict__ bk, const float* __restrict__ bv,
    u16* __restrict__ qws, u16* __restrict__ kws, u16* __restrict__ vws)
{
  __shared__ u16 Al[2][128 * 64];
  __shared__ u16 Bl[2][128 * 64];
  const int z = blockIdx.z;
  const float* Xf = (z == 0) ? qf32 : (z == 1) ? kf32 : vf32;
  const u16* Wb = wb + (size_t)z * 1048576;
  const float* bias = (z == 0) ? bq : (z == 1) ? bk : bv;
  const float bscale = (z == 0) ? QSCALE : 1.0f;

  const int t = threadIdx.x;
  const int l = t & 63, w = t >> 6;        // 8 waves
  const int lr = l & 15, lg = l >> 4;
  const int wm = w >> 2, wn = w & 3;       // 2 x 4 wave grid
  const int m0 = blockIdx.x * 128, n0 = blockIdx.y * 128;
  const int sxr = lr & 7;

  f32x4 acc[4][2] = {};
  float4 areg[2][2];

  ASTAGE_LOAD8(areg, Xf, 0)
  GSTAGE8(&Bl[0][0], Wb + (size_t)n0 * 1024)
  ASTAGE_WRITE8(&Al[0][0], areg)
  ASTAGE_LOAD8(areg, Xf, 64)

  for (int i = 0; i < 16; ++i) {
    __syncthreads();
    if (i < 15) {
      GSTAGE8(&Bl[(i + 1) & 1][0], Wb + (size_t)n0 * 1024 + (i + 1) * 64)
      ASTAGE_WRITE8(&Al[(i + 1) & 1][0], areg)
    }
    if (i < 14) ASTAGE_LOAD8(areg, Xf, (i + 2) * 64)

    const u16* Ab_ = &Al[i & 1][0];
    const u16* Bb_ = &Bl[i & 1][0];

    bf16x8 a[4][2], b[2][2];
#pragma unroll
    for (int mi = 0; mi < 4; ++mi) {
      const u16* rp = Ab_ + (wm * 64 + mi * 16 + lr) * 64;
      a[mi][0] = *(const bf16x8*)(rp + ((lg ^ sxr) * 8));
      a[mi][1] = *(const bf16x8*)(rp + (((4 + lg) ^ sxr) * 8));
    }
#pragma unroll
    for (int ni = 0; ni < 2; ++ni) {
      const u16* rp = Bb_ + (wn * 32 + ni * 16 + lr) * 64;
      b[ni][0] = *(const bf16x8*)(rp + ((lg ^ sxr) * 8));
      b[ni][1] = *(const bf16x8*)(rp + (((4 + lg) ^ sxr) * 8));
    }
    __builtin_amdgcn_s_setprio(1);
#pragma unroll
    for (int mi = 0; mi < 4; ++mi)
#pragma unroll
      for (int ni = 0; ni < 2; ++ni) {
        acc[mi][ni] = __builtin_amdgcn_mfma_f32_16x16x32_bf16(a[mi][0], b[ni][0], acc[mi][ni], 0, 0, 0);
        acc[mi][ni] = __builtin_amdgcn_mfma_f32_16x16x32_bf16(a[mi][1], b[ni][1], acc[mi][ni], 0, 0, 0);
      }
    __builtin_amdgcn_s_setprio(0);
  }

#pragma unroll
  for (int mi = 0; mi < 4; ++mi) {
#pragma unroll
    for (int ni = 0; ni < 2; ++ni) {
#pragma unroll
      for (int r = 0; r < 4; ++r) {
        int m = m0 + wm * 64 + mi * 16 + lg * 4 + r;
        int n = n0 + wn * 32 + ni * 16 + lr;
        float y = acc[mi][ni][r] + bias[n] * bscale;
        u16 h = f2bf(y);
        int b_ = m >> 11, s = m & 2047, hh = n >> 6, d = n & 63;
        size_t head = (size_t)(b_ * NH + hh);
        if (z == 0)      qws[head * BHD + (size_t)s * DK + d] = h;
        else if (z == 1) kws[head * BHD + (size_t)s * DK + d] = h;
        else             vws[head * BHD + (size_t)d * S_LEN + s] = h;  // V transposed
      }
    }
  }
}

// ---------------- output projection GEMM: out = Ab(bf16) @ Wob^T + bo (fp32 out) ----------
// 8-wave/512-thread transplant of the R24 proj geometry (A already bf16 -> GSTAGE8 path).
__global__ __launch_bounds__(512, 4) void oproj_gemm(
    const u16* __restrict__ Ab, const u16* __restrict__ Wob,
    const float* __restrict__ bo, float* __restrict__ out)
{
  __shared__ u16 Al[2][128 * 64];
  __shared__ u16 Bl[2][128 * 64];
  const int t = threadIdx.x;
  const int l = t & 63, w = t >> 6;        // 8 waves
  const int lr = l & 15, lg = l >> 4;
  const int wm = w >> 2, wn = w & 3;       // 2 x 4 wave grid
  const int m0 = blockIdx.x * 128, n0 = blockIdx.y * 128;
  const int sxr = lr & 7;

  f32x4 acc[4][2] = {};

  GSTAGE8(&Al[0][0], Ab + (size_t)m0 * 1024)
  GSTAGE8(&Bl[0][0], Wob + (size_t)n0 * 1024)

  for (int i = 0; i < 16; ++i) {
    __syncthreads();
    if (i < 15) {
      GSTAGE8(&Al[(i + 1) & 1][0], Ab + (size_t)m0 * 1024 + (i + 1) * 64)
      GSTAGE8(&Bl[(i + 1) & 1][0], Wob + (size_t)n0 * 1024 + (i + 1) * 64)
    }
    const u16* Ab_ = &Al[i & 1][0];
    const u16* Bb_ = &Bl[i & 1][0];

    bf16x8 a[4][2], b[2][2];
#pragma unroll
    for (int mi = 0; mi < 4; ++mi) {
      const u16* rp = Ab_ + (wm * 64 + mi * 16 + lr) * 64;
      a[mi][0] = *(const bf16x8*)(rp + ((lg ^ sxr) * 8));
      a[mi][1] = *(const bf16x8*)(rp + (((4 + lg) ^ sxr) * 8));
    }
#pragma unroll
    for (int ni = 0; ni < 2; ++ni) {
      const u16* rp = Bb_ + (wn * 32 + ni * 16 + lr) * 64;
      b[ni][0] = *(const bf16x8*)(rp + ((lg ^ sxr) * 8));
      b[ni][1] = *(const bf16x8*)(rp + (((4 + lg) ^ sxr) * 8));
    }
    __builtin_amdgcn_s_setprio(1);
#pragma unroll
    for (int mi = 0; mi < 4; ++mi)
#pragma unroll
      for (int ni = 0; ni < 2; ++ni) {
        acc[mi][ni] = __builtin_amdgcn_mfma_f32_16x16x32_bf16(a[mi][0], b[ni][0], acc[mi][ni], 0, 0, 0);
        acc[mi][ni] = __builtin_amdgcn_mfma_f32_16x16x32_bf16(a[mi][1], b[ni][1], acc[mi][ni], 0, 0, 0);
      }
    __builtin_amdgcn_s_setprio(0);
  }

#pragma unroll
  for (int mi = 0; mi < 4; ++mi) {
#pragma unroll
    for (int ni = 0; ni < 2; ++ni) {
#pragma unroll
      for (int r = 0; r < 4; ++r) {
        int m = m0 + wm * 64 + mi * 16 + lg * 4 + r;
        int n = n0 + wn * 32 + ni * 16 + lr;
        out[(size_t)m * DM + n] = acc[mi][ni][r] + bo[n];
      }
    }
  }
}

// ---------------- flash attention (unchanged from R16 — validated) -------------------------
__global__ __launch_bounds__(256, 4) void attn_kernel(
    const u16* __restrict__ qh, const u16* __restrict__ kh,
    const u16* __restrict__ vt, u16* __restrict__ aout)
{
  __shared__ u16 KT[2][64 * 64];
  __shared__ u16 VT[2][64 * 64];

  const int t = threadIdx.x;
  const int l = t & 63, w = t >> 6;      // 4 waves
  const int lr = l & 15, lg = l >> 4;

  const int bid = blockIdx.x;
  const int logical = (bid & 7) * 128 + (bid >> 3);
  const int bh = logical >> 4;               // 16 blocks per head
  const int qb = (logical & 15) * 128 + w * 32;

  const u16* qp = qh + (size_t)bh * BHD;
  const u16* kp = kh + (size_t)bh * BHD;
  const u16* vp = vt + (size_t)bh * BHD;
  const int sx = lr & 7;

  const int srow = t >> 3;                   // 0..31
  const int scolS = (t & 7) ^ (srow & 7);    // inverse-swizzled source 16B-chunk

  bf16x8 qf[2][2];
#pragma unroll
  for (int qi = 0; qi < 2; ++qi)
#pragma unroll
    for (int c = 0; c < 2; ++c)
      qf[qi][c] = *(const bf16x8*)(qp + (size_t)(qb + qi * 16 + lr) * DK + c * 32 + lg * 8);

  bf16x8 onesf;
#pragma unroll
  for (int e = 0; e < 8; ++e) onesf[e] = (short)0x3F80;

  f32x4 acc[4][2] = {};
  f32x4 acc_l[2] = {};

#define STAGE(B, KV)                                                                  \
  {                                                                                   \
    _Pragma("unroll") for (int j = 0; j < 2; ++j) {                                   \
      gload_lds16(kp + (size_t)((KV) + j * 32 + srow) * DK + scolS * 8,               \
                  &KT[B][j * 2048 + w * 512]);                                        \
      gload_lds16(vp + (size_t)(j * 32 + srow) * S_LEN + (KV) + scolS * 8,            \
                  &VT[B][j * 2048 + w * 512]);                                        \
    }                                                                                 \
  }

  STAGE(0, 0)

  for (int i = 0; i < 32; ++i) {
    __syncthreads();
    if (i < 31) STAGE((i + 1) & 1, (i + 1) * 64)

    const u16* Kb = &KT[i & 1][0];
    const u16* Vb = &VT[i & 1][0];

    f32x4 sc[4][2] = {};
    __builtin_amdgcn_s_setprio(1);
#pragma unroll
    for (int ct = 0; ct < 4; ++ct) {
      bf16x8 k0 = *(const bf16x8*)(Kb + (ct * 16 + lr) * 64 + ((lg ^ sx) * 8));
      bf16x8 k1 = *(const bf16x8*)(Kb + (ct * 16 + lr) * 64 + (((4 + lg) ^ sx) * 8));
      sc[ct][0] = __builtin_amdgcn_mfma_f32_16x16x32_bf16(k0, qf[0][0], sc[ct][0], 0, 0, 0);
      sc[ct][0] = __builtin_amdgcn_mfma_f32_16x16x32_bf16(k1, qf[0][1], sc[ct][0], 0, 0, 0);
      sc[ct][1] = __builtin_amdgcn_mfma_f32_16x16x32_bf16(k0, qf[1][0], sc[ct][1], 0, 0, 0);
      sc[ct][1] = __builtin_amdgcn_mfma_f32_16x16x32_bf16(k1, qf[1][1], sc[ct][1], 0, 0, 0);
    }
    __builtin_amdgcn_s_setprio(0);

    unsigned cpk[2][4][2];
#pragma unroll
    for (int qi = 0; qi < 2; ++qi) {
#pragma unroll
      for (int ct = 0; ct < 4; ++ct) {
        float p0 = __builtin_amdgcn_exp2f(sc[ct][qi][0]);
        float p1 = __builtin_amdgcn_exp2f(sc[ct][qi][1]);
        float p2 = __builtin_amdgcn_exp2f(sc[ct][qi][2]);
        float p3 = __builtin_amdgcn_exp2f(sc[ct][qi][3]);
        asm("v_cvt_pk_bf16_f32 %0, %1, %2" : "=v"(cpk[qi][ct][0]) : "v"(p0), "v"(p1));
        asm("v_cvt_pk_bf16_f32 %0, %1, %2" : "=v"(cpk[qi][ct][1]) : "v"(p2), "v"(p3));
      }
    }

    bf16x8 pf[2][2];
#pragma unroll
    for (int qi = 0; qi < 2; ++qi)
#pragma unroll
      for (int kk = 0; kk < 2; ++kk) {
        unsigned a0 = cpk[qi][2 * kk][0], b0 = cpk[qi][2 * kk + 1][0];
        unsigned a1 = cpk[qi][2 * kk][1], b1 = cpk[qi][2 * kk + 1][1];
        asm("v_permlane32_swap_b32 %0, %1" : "+v"(a0), "+v"(b0));
        asm("v_permlane16_swap_b32 %0, %1" : "+v"(a0), "+v"(b0));
        asm("v_permlane32_swap_b32 %0, %1" : "+v"(a1), "+v"(b1));
        asm("v_permlane16_swap_b32 %0, %1" : "+v"(a1), "+v"(b1));
        union { unsigned u[4]; bf16x8 v; } tmp;
        tmp.u[0] = a0; tmp.u[1] = a1; tmp.u[2] = b0; tmp.u[3] = b1;
        pf[qi][kk] = tmp.v;
      }

    __builtin_amdgcn_s_setprio(1);
    acc_l[0] = __builtin_amdgcn_mfma_f32_16x16x32_bf16(pf[0][0], onesf, acc_l[0], 0, 0, 0);
    acc_l[0] = __builtin_amdgcn_mfma_f32_16x16x32_bf16(pf[0][1], onesf, acc_l[0], 0, 0, 0);
    acc_l[1] = __builtin_amdgcn_mfma_f32_16x16x32_bf16(pf[1][0], onesf, acc_l[1], 0, 0, 0);
    acc_l[1] = __builtin_amdgcn_mfma_f32_16x16x32_bf16(pf[1][1], onesf, acc_l[1], 0, 0, 0);
#pragma unroll
    for (int ni = 0; ni < 4; ++ni) {
      bf16x8 vf0 = *(const bf16x8*)(Vb + (ni * 16 + lr) * 64 + ((lg ^ sx) * 8));
      bf16x8 vf1 = *(const bf16x8*)(Vb + (ni * 16 + lr) * 64 + (((4 + lg) ^ sx) * 8));
      acc[ni][0] = __builtin_amdgcn_mfma_f32_16x16x32_bf16(pf[0][0], vf0, acc[ni][0], 0, 0, 0);
      acc[ni][0] = __builtin_amdgcn_mfma_f32_16x16x32_bf16(pf[0][1], vf1, acc[ni][0], 0, 0, 0);
      acc[ni][1] = __builtin_amdgcn_mfma_f32_16x16x32_bf16(pf[1][0], vf0, acc[ni][1], 0, 0, 0);
      acc[ni][1] = __builtin_amdgcn_mfma_f32_16x16x32_bf16(pf[1][1], vf1, acc[ni][1], 0, 0, 0);
    }
    __builtin_amdgcn_s_setprio(0);
  }
#undef STAGE

  const int b_ = bh >> 4, hh = bh & 15;
#pragma unroll
  for (int qi = 0; qi < 2; ++qi) {
#pragma unroll
    for (int r = 0; r < 4; ++r) {
      float inv = 1.0f / acc_l[qi][r];
      int s = qb + qi * 16 + lg * 4 + r;
#pragma unroll
      for (int ni = 0; ni < 4; ++ni)
        aout[((size_t)(b_ * S_LEN + s)) * DM + hh * DK + ni * 16 + lr] =
            f2bf(acc[ni][qi][r] * inv);
    }
  }
}

extern "C" void kernel_launch(void* const* d_in, const int* in_sizes, int n_in,
                              void* d_out, int out_size, void* d_ws, size_t ws_size,
                              hipStream_t stream) {
  (void)in_sizes; (void)n_in; (void)out_size; (void)ws_size;
  const float* q  = (const float*)d_in[0];
  const float* k  = (const float*)d_in[1];
  const float* v  = (const float*)d_in[2];
  const float* Wq = (const float*)d_in[3];
  const float* bq = (const float*)d_in[4];
  const float* Wk = (const float*)d_in[5];
  const float* bk = (const float*)d_in[6];
  const float* Wv = (const float*)d_in[7];
  const float* bv = (const float*)d_in[8];
  const float* Wo = (const float*)d_in[9];
  const float* bo = (const float*)d_in[10];
  float* out = (float*)d_out;

  // ws (u16 units): qws|kws|vws (8M each) | aws (8M) | wb (4 x 1M) => 36700160 u16 = 73.4 MB
  u16* qws = (u16*)d_ws;
  u16* kws = qws + (size_t)8388608;
  u16* vws = kws + (size_t)8388608;
  u16* aws = vws + (size_t)8388608;   // attn output bf16
  u16* wb  = aws + (size_t)8388608;   // Wq(scaled)|Wk|Wv|Wo bf16

  conv_w<<<dim3(4096), dim3(256), 0, stream>>>(Wq, Wk, Wv, Wo, wb);

  proj_gemm<<<dim3(64, 8, 3), dim3(512), 0, stream>>>(q, k, v, wb, bq, bk, bv,
                                                      qws, kws, vws);

  attn_kernel<<<dim3(1024), dim3(256), 0, stream>>>(qws, kws, vws, aws);

  oproj_gemm<<<dim3(64, 8), dim3(512), 0, stream>>>(aws, wb + 3145728, bo, out);
}